// Round 5
// baseline (328.956 us; speedup 1.0000x reference)
//
#include <hip/hip_runtime.h>

// ---------------------------------------------------------------------------
// TextGraphSAGE: 2-layer SAGEConv (mean aggr), N=50000, D=768, H=128, C=4,
// E=800000.
//  - project BEFORE aggregating (mean commutes with linear map)
//  - CSR gather instead of scatter atomics (r1: 102M float atomics = 77%)
//  - r2: fused bf16-MFMA projection GEMM (x read once)
//  - r4 profile: hipMemsetAsync's blit kernel cost 87us (!) -> own zero
//    kernel; gemm latency-bound at 37% occ with LDS staging -> r5 uses a
//    barrier-free direct-register GEMM (B is 384KB, L2-resident; A frags
//    loaded global->reg->cvt). No LDS, no syncthreads, no bank conflicts.
// ---------------------------------------------------------------------------

typedef __bf16 bf16x8 __attribute__((ext_vector_type(8)));
typedef float  f32x4  __attribute__((ext_vector_type(4)));

__device__ __forceinline__ float bf16_lo(uint32_t w) {
    union { uint32_t u; float f; } c; c.u = w << 16; return c.f;
}
__device__ __forceinline__ float bf16_hi(uint32_t w) {
    union { uint32_t u; float f; } c; c.u = w & 0xffff0000u; return c.f;
}

// ---- W pack: Wb[256][768] bf16 = concat(W1l, W1r) rows
__global__ __launch_bounds__(256)
void convert_w(const float* __restrict__ W1l, const float* __restrict__ W1r,
               __bf16* __restrict__ Wb)
{
    int i = blockIdx.x * 256 + threadIdx.x;
    if (i >= 256 * 768) return;
    int n = i / 768, k = i - n * 768;
    float v = (n < 128) ? W1l[n * 768 + k] : W1r[(n - 128) * 768 + k];
    Wb[i] = (__bf16)v;
}

// ---- fused layer-1 projection: pq[M][256](bf16) = x[M][768] @ Wb[256][768]^T
// Direct-register MFMA GEMM: no LDS, no barriers. Block = 64 rows x 128 cols,
// 4 waves in 2x2; each wave owns 32 rows x 64 cols (acc[2][4] of 16x16).
__global__ __launch_bounds__(256)
void gemm_direct(const float* __restrict__ A, const __bf16* __restrict__ Bw,
                 __bf16* __restrict__ Cb, int M)
{
    const int bm   = blockIdx.x * 64;
    const int bn   = blockIdx.y * 128;
    const int lane = threadIdx.x & 63;
    const int wave = threadIdx.x >> 6;
    const int wr = wave >> 1, wc = wave & 1;
    const int l15 = lane & 15;
    const int lk  = lane >> 4;               // 0..3

    f32x4 acc[2][4] = {};

    // base row addresses (clamped; garbage acc rows are never stored)
    const float* arow[2];
    #pragma unroll
    for (int i = 0; i < 2; ++i) {
        int row = bm + wr * 32 + i * 16 + l15;
        row = min(row, M - 1);
        arow[i] = A + (size_t)row * 768;
    }
    const __bf16* brow[4];
    #pragma unroll
    for (int j = 0; j < 4; ++j)
        brow[j] = Bw + (size_t)(bn + wc * 64 + j * 16 + l15) * 768;

    for (int kt = 0; kt < 12; ++kt) {
        #pragma unroll
        for (int ks = 0; ks < 2; ++ks) {
            const int k = kt * 64 + ks * 32 + lk * 8;
            bf16x8 af[2], bfr[4];
            #pragma unroll
            for (int i = 0; i < 2; ++i) {
                float4 f0 = *(const float4*)(arow[i] + k);
                float4 f1 = *(const float4*)(arow[i] + k + 4);
                bf16x8 a;
                a[0] = (__bf16)f0.x; a[1] = (__bf16)f0.y;
                a[2] = (__bf16)f0.z; a[3] = (__bf16)f0.w;
                a[4] = (__bf16)f1.x; a[5] = (__bf16)f1.y;
                a[6] = (__bf16)f1.z; a[7] = (__bf16)f1.w;
                af[i] = a;
            }
            #pragma unroll
            for (int j = 0; j < 4; ++j)
                bfr[j] = *(const bf16x8*)(brow[j] + k);
            #pragma unroll
            for (int i = 0; i < 2; ++i)
                #pragma unroll
                for (int j = 0; j < 4; ++j)
                    acc[i][j] = __builtin_amdgcn_mfma_f32_16x16x32_bf16(
                        af[i], bfr[j], acc[i][j], 0, 0, 0);
        }
    }

    // C/D layout: col = lane&15, row = (lane>>4)*4 + reg  [m89-verified]
    #pragma unroll
    for (int i = 0; i < 2; ++i)
        #pragma unroll
        for (int j = 0; j < 4; ++j)
            #pragma unroll
            for (int v = 0; v < 4; ++v) {
                int row = bm + wr * 32 + i * 16 + lk * 4 + v;
                int col = bn + wc * 64 + j * 16 + l15;
                if (row < M) Cb[(size_t)row * 256 + col] = (__bf16)acc[i][j][v];
            }
}

// ---- zero the degree array (hipMemsetAsync's blit kernel cost 87us)
__global__ __launch_bounds__(256)
void zero_deg(int* __restrict__ deg, int N)
{
    int i = blockIdx.x * 256 + threadIdx.x;
    if (i < N) deg[i] = 0;
}

// ---- CSR build step 1: degree histogram
__global__ __launch_bounds__(256)
void csr_count(const int* __restrict__ ei, int* __restrict__ deg, int E)
{
    int e = blockIdx.x * 256 + threadIdx.x;
    if (e >= E) return;
    atomicAdd(&deg[ei[E + e]], 1);
}

// ---- scan step 1: per-1024-block exclusive scan + block totals
__global__ __launch_bounds__(1024)
void scan1(const int* __restrict__ deg, int* __restrict__ row_ptr,
           int* __restrict__ partials, int N)
{
    __shared__ int buf[1024];
    int i = blockIdx.x * 1024 + threadIdx.x;
    int v = (i < N) ? deg[i] : 0;
    int val = v;
    buf[threadIdx.x] = val;
    __syncthreads();
    for (int off = 1; off < 1024; off <<= 1) {
        int t = (threadIdx.x >= (unsigned)off) ? buf[threadIdx.x - off] : 0;
        __syncthreads();
        val += t;
        buf[threadIdx.x] = val;
        __syncthreads();
    }
    if (i < N) row_ptr[i] = val - v;
    if (threadIdx.x == 1023) partials[blockIdx.x] = val;
}

// ---- scan step 2: exclusive scan of <=64 block totals (one wave)
__global__ __launch_bounds__(64)
void scan2(int* __restrict__ partials, int nb, int* __restrict__ row_ptr,
           int N, int E)
{
    int lane = threadIdx.x;
    int v = (lane < nb) ? partials[lane] : 0;
    int s = v;
    #pragma unroll
    for (int off = 1; off < 64; off <<= 1) {
        int t = __shfl_up(s, off);
        if (lane >= off) s += t;
    }
    if (lane < nb) partials[lane] = s - v;
    if (lane == 0) row_ptr[N] = E;
}

// ---- scan step 3: add block offsets, init cursors
__global__ __launch_bounds__(1024)
void scan3(int* __restrict__ row_ptr, int* __restrict__ cursor,
           const int* __restrict__ partials, int N)
{
    int i = blockIdx.x * 1024 + threadIdx.x;
    if (i >= N) return;
    int v = row_ptr[i] + partials[blockIdx.x];
    row_ptr[i] = v;
    cursor[i]  = v;
}

// ---- CSR build step 3: scatter src ids into per-dst slots
__global__ __launch_bounds__(256)
void csr_fill(const int* __restrict__ ei, int* __restrict__ cursor,
              int* __restrict__ csr_src, int E)
{
    int e = blockIdx.x * 256 + threadIdx.x;
    if (e >= E) return;
    int src = ei[e];
    int dst = ei[E + e];
    int pos = atomicAdd(&cursor[dst], 1);
    csr_src[pos] = src;
}

// ---- layer 1 + layer-2 projection, fused. One wave per node.
__global__ __launch_bounds__(256)
void sage1_fused(const int* __restrict__ row_ptr, const int* __restrict__ csr_src,
                 const __bf16* __restrict__ pq, const float* __restrict__ b1,
                 const float* __restrict__ W2l, const float* __restrict__ W2r,
                 float* __restrict__ r, float* __restrict__ s, int N)
{
    __shared__ float Wl[512], Wr[512];
    for (int i = threadIdx.x; i < 512; i += 256) {
        Wl[i] = W2l[i];
        Wr[i] = W2r[i];
    }
    __syncthreads();

    int wid  = threadIdx.x >> 6;
    int lane = threadIdx.x & 63;
    int n = blockIdx.x * 4 + wid;
    if (n >= N) return;
    int beg = row_ptr[n], end = row_ptr[n + 1];

    float ax = 0.f, ay = 0.f;
    for (int eb = beg; eb < end; eb += 64) {
        int cnt = min(64, end - eb);
        int id = (eb + lane < end) ? csr_src[eb + lane] : 0;
        for (int t = 0; t < cnt; ++t) {
            int src = __shfl(id, t);
            uint32_t w = *(const uint32_t*)(pq + (size_t)src * 256 + lane * 2);
            ax += bf16_lo(w);
            ay += bf16_hi(w);
        }
    }
    float inv = 1.0f / fmaxf((float)(end - beg), 1.0f);
    uint32_t qw = *(const uint32_t*)(pq + (size_t)n * 256 + 128 + lane * 2);
    float hx = fmaxf(ax * inv + b1[2 * lane]     + bf16_lo(qw), 0.f);
    float hy = fmaxf(ay * inv + b1[2 * lane + 1] + bf16_hi(qw), 0.f);

    float part[8];
    #pragma unroll
    for (int c = 0; c < 4; ++c) {
        part[c]     = hx * Wl[c * 128 + 2 * lane] + hy * Wl[c * 128 + 2 * lane + 1];
        part[4 + c] = hx * Wr[c * 128 + 2 * lane] + hy * Wr[c * 128 + 2 * lane + 1];
    }
    #pragma unroll
    for (int off = 32; off; off >>= 1)
        #pragma unroll
        for (int c = 0; c < 8; ++c)
            part[c] += __shfl_xor(part[c], off);
    if (lane == 0) {
        *(float4*)(r + (size_t)n * 4) = make_float4(part[0], part[1], part[2], part[3]);
        *(float4*)(s + (size_t)n * 4) = make_float4(part[4], part[5], part[6], part[7]);
    }
}

// ---- layer 2: out[n] = mean_{src} r[src] + b2 + s[n]
__global__ __launch_bounds__(256)
void sage2_gather(const int* __restrict__ row_ptr, const int* __restrict__ csr_src,
                  const float* __restrict__ r, const float* __restrict__ s,
                  const float* __restrict__ b2, float* __restrict__ out, int N)
{
    int t = blockIdx.x * 256 + threadIdx.x;
    if (t >= N * 4) return;
    int n = t >> 2, c = t & 3;
    int beg = row_ptr[n], end = row_ptr[n + 1];
    float acc = 0.f;
    for (int e = beg; e < end; ++e)
        acc += r[(size_t)csr_src[e] * 4 + c];
    out[t] = acc / fmaxf((float)(end - beg), 1.0f) + b2[c] + s[t];
}

extern "C" void kernel_launch(void* const* d_in, const int* in_sizes, int n_in,
                              void* d_out, int out_size, void* d_ws, size_t ws_size,
                              hipStream_t stream)
{
    const float* x   = (const float*)d_in[0];
    const int*   ei  = (const int*)d_in[1];
    const float* W1l = (const float*)d_in[2];
    const float* b1l = (const float*)d_in[3];
    const float* W1r = (const float*)d_in[4];
    const float* W2l = (const float*)d_in[5];
    const float* b2l = (const float*)d_in[6];
    const float* W2r = (const float*)d_in[7];
    float* out = (float*)d_out;

    const int N = in_sizes[0] / 768;   // 50000
    const int E = in_sizes[1] / 2;     // 800000
    const int NB = (N + 1023) / 1024;  // 49 scan blocks

    char* ws = (char*)d_ws;
    size_t off = 0;
    auto alloc = [&](size_t bytes) -> void* {
        void* pp = ws + off;
        off += (bytes + 255) & ~(size_t)255;
        return pp;
    };
    __bf16* pq      = (__bf16*)alloc((size_t)N * 256 * 2);
    float*  r       = (float*)alloc((size_t)N * 4 * 4);
    float*  s       = (float*)alloc((size_t)N * 4 * 4);
    __bf16* Wb      = (__bf16*)alloc((size_t)256 * 768 * 2);
    int*    deg     = (int*)alloc((size_t)N * 4);
    int*    row_ptr = (int*)alloc((size_t)(N + 1) * 4);
    int*    cursor  = (int*)alloc((size_t)N * 4);
    int*    csr_src = (int*)alloc((size_t)E * 4);
    int*    partials= (int*)alloc((size_t)64 * 4);

    // ---- fused layer-1 projection (bf16 MFMA): pq = x @ [W1l;W1r]^T
    convert_w<<<(256 * 768 + 255) / 256, 256, 0, stream>>>(W1l, W1r, Wb);
    dim3 gg((N + 63) / 64, 2);
    gemm_direct<<<gg, 256, 0, stream>>>(x, Wb, pq, N);

    // ---- CSR build
    zero_deg<<<(N + 255) / 256, 256, 0, stream>>>(deg, N);
    csr_count<<<(E + 255) / 256, 256, 0, stream>>>(ei, deg, E);
    scan1<<<NB, 1024, 0, stream>>>(deg, row_ptr, partials, N);
    scan2<<<1, 64, 0, stream>>>(partials, NB, row_ptr, N, E);
    scan3<<<NB, 1024, 0, stream>>>(row_ptr, cursor, partials, N);
    csr_fill<<<(E + 255) / 256, 256, 0, stream>>>(ei, cursor, csr_src, E);

    // ---- layer 1 aggregate + epilogue + layer-2 projection (fused)
    sage1_fused<<<(N + 3) / 4, 256, 0, stream>>>(row_ptr, csr_src, pq, b1l,
                                                 W2l, W2r, r, s, N);

    // ---- layer 2 aggregate + epilogue
    sage2_gather<<<(N * 4 + 255) / 256, 256, 0, stream>>>(row_ptr, csr_src, r, s, b2l, out, N);
}

// Round 6
// 268.280 us; speedup vs baseline: 1.2262x; 1.2262x over previous
//
#include <hip/hip_runtime.h>

// ---------------------------------------------------------------------------
// TextGraphSAGE: 2-layer SAGEConv (mean aggr), N=50000, D=768, H=128, C=4,
// E=800000.
//  - project BEFORE aggregating (mean commutes with linear map)
//  - CSR gather instead of scatter atomics (r1: 102M float atomics = 77%)
//  - r4: own zero kernel (hipMemsetAsync blit cost 87us)
//  - r5 post-mortem: direct-register GEMM regressed (no staging burst ->
//    MLP collapse, hbm 1.8->0.95 TB/s). r6: back to LDS staging +
//    reg-prefetch, tile 64x64 (18.4KB LDS, 3128 blocks), grid flipped so
//    same-bm blocks are consecutive (A re-read stays in L2/LLC).
// ---------------------------------------------------------------------------

typedef __bf16 bf16x8 __attribute__((ext_vector_type(8)));
typedef float  f32x4  __attribute__((ext_vector_type(4)));

__device__ __forceinline__ float bf16_lo(uint32_t w) {
    union { uint32_t u; float f; } c; c.u = w << 16; return c.f;
}
__device__ __forceinline__ float bf16_hi(uint32_t w) {
    union { uint32_t u; float f; } c; c.u = w & 0xffff0000u; return c.f;
}

// ---- W pack: Wb[256][768] bf16 = concat(W1l, W1r) rows
__global__ __launch_bounds__(256)
void convert_w(const float* __restrict__ W1l, const float* __restrict__ W1r,
               __bf16* __restrict__ Wb)
{
    int i = blockIdx.x * 256 + threadIdx.x;
    if (i >= 256 * 768) return;
    int n = i / 768, k = i - n * 768;
    float v = (n < 128) ? W1l[n * 768 + k] : W1r[(n - 128) * 768 + k];
    Wb[i] = (__bf16)v;
}

// ---- fused layer-1 projection: pq[M][256](bf16) = x[M][768] @ Wb[256][768]^T
// 64x64 tile, 4 waves (2x2, 32x32 each), LDS staging + reg-prefetch pipeline.
// blockIdx.x = bn slice (fast-varying -> A-tile L2 reuse), blockIdx.y = bm.
__global__ __launch_bounds__(256)
void gemm_bf16(const float* __restrict__ A, const __bf16* __restrict__ Bw,
               __bf16* __restrict__ Cb, int M)
{
    constexpr int LDK = 72;                  // +8 bf16 pad (144B row stride)
    __shared__ __bf16 As[64][LDK];           // 9.2 KB
    __shared__ __bf16 Bs[64][LDK];           // 9.2 KB
    const int bn   = blockIdx.x * 64;
    const int bm   = blockIdx.y * 64;
    const int tid  = threadIdx.x;
    const int lane = tid & 63;
    const int wave = tid >> 6;
    const int wr = wave >> 1, wc = wave & 1; // wave tile: 32 rows x 32 cols
    const int l15 = lane & 15;
    const int lk  = lane >> 4;               // 0..3

    f32x4 acc[2][2] = {};
    float4 apref[2][2];
    bf16x8 bpref[2];

    auto load_tile = [&](int k0) {
        #pragma unroll
        for (int it = 0; it < 2; ++it) {
            int v = it * 256 + tid;
            int row = v >> 3, kc = (v & 7) << 3;
            if (bm + row < M) {
                const float* src = A + (size_t)(bm + row) * 768 + k0 + kc;
                apref[it][0] = *(const float4*)src;
                apref[it][1] = *(const float4*)(src + 4);
            } else {
                apref[it][0] = make_float4(0.f, 0.f, 0.f, 0.f);
                apref[it][1] = make_float4(0.f, 0.f, 0.f, 0.f);
            }
            bpref[it] = *(const bf16x8*)(Bw + (size_t)(bn + row) * 768 + k0 + kc);
        }
    };

    load_tile(0);
    for (int kt = 0; kt < 12; ++kt) {
        if (kt) __syncthreads();             // MFMA of kt-1 done with LDS
        #pragma unroll
        for (int it = 0; it < 2; ++it) {
            int v = it * 256 + tid;
            int row = v >> 3, kc = (v & 7) << 3;
            float4 f0 = apref[it][0], f1 = apref[it][1];
            bf16x8 b;
            b[0] = (__bf16)f0.x; b[1] = (__bf16)f0.y;
            b[2] = (__bf16)f0.z; b[3] = (__bf16)f0.w;
            b[4] = (__bf16)f1.x; b[5] = (__bf16)f1.y;
            b[6] = (__bf16)f1.z; b[7] = (__bf16)f1.w;
            *(bf16x8*)&As[row][kc] = b;
            *(bf16x8*)&Bs[row][kc] = bpref[it];
        }
        __syncthreads();
        if (kt < 11) load_tile((kt + 1) * 64);   // in flight across MFMA

        #pragma unroll
        for (int ks = 0; ks < 2; ++ks) {
            int koff = ks * 32 + lk * 8;
            bf16x8 af[2], bfr[2];
            #pragma unroll
            for (int i = 0; i < 2; ++i)
                af[i] = *(const bf16x8*)&As[wr * 32 + i * 16 + l15][koff];
            #pragma unroll
            for (int j = 0; j < 2; ++j)
                bfr[j] = *(const bf16x8*)&Bs[wc * 32 + j * 16 + l15][koff];
            #pragma unroll
            for (int i = 0; i < 2; ++i)
                #pragma unroll
                for (int j = 0; j < 2; ++j)
                    acc[i][j] = __builtin_amdgcn_mfma_f32_16x16x32_bf16(
                        af[i], bfr[j], acc[i][j], 0, 0, 0);
        }
    }

    // C/D layout: col = lane&15, row = (lane>>4)*4 + reg  [m89-verified]
    #pragma unroll
    for (int i = 0; i < 2; ++i)
        #pragma unroll
        for (int j = 0; j < 2; ++j)
            #pragma unroll
            for (int v = 0; v < 4; ++v) {
                int row = bm + wr * 32 + i * 16 + lk * 4 + v;
                int col = bn + wc * 32 + j * 16 + l15;
                if (row < M) Cb[(size_t)row * 256 + col] = (__bf16)acc[i][j][v];
            }
}

// ---- zero the degree array (hipMemsetAsync's blit kernel cost 87us)
__global__ __launch_bounds__(256)
void zero_deg(int* __restrict__ deg, int N)
{
    int i = blockIdx.x * 256 + threadIdx.x;
    if (i < N) deg[i] = 0;
}

// ---- CSR build step 1: degree histogram
__global__ __launch_bounds__(256)
void csr_count(const int* __restrict__ ei, int* __restrict__ deg, int E)
{
    int e = blockIdx.x * 256 + threadIdx.x;
    if (e >= E) return;
    atomicAdd(&deg[ei[E + e]], 1);
}

// ---- scan step 1: per-1024-block exclusive scan + block totals
__global__ __launch_bounds__(1024)
void scan1(const int* __restrict__ deg, int* __restrict__ row_ptr,
           int* __restrict__ partials, int N)
{
    __shared__ int buf[1024];
    int i = blockIdx.x * 1024 + threadIdx.x;
    int v = (i < N) ? deg[i] : 0;
    int val = v;
    buf[threadIdx.x] = val;
    __syncthreads();
    for (int off = 1; off < 1024; off <<= 1) {
        int t = (threadIdx.x >= (unsigned)off) ? buf[threadIdx.x - off] : 0;
        __syncthreads();
        val += t;
        buf[threadIdx.x] = val;
        __syncthreads();
    }
    if (i < N) row_ptr[i] = val - v;
    if (threadIdx.x == 1023) partials[blockIdx.x] = val;
}

// ---- scan step 2: exclusive scan of <=64 block totals (one wave)
__global__ __launch_bounds__(64)
void scan2(int* __restrict__ partials, int nb, int* __restrict__ row_ptr,
           int N, int E)
{
    int lane = threadIdx.x;
    int v = (lane < nb) ? partials[lane] : 0;
    int s = v;
    #pragma unroll
    for (int off = 1; off < 64; off <<= 1) {
        int t = __shfl_up(s, off);
        if (lane >= off) s += t;
    }
    if (lane < nb) partials[lane] = s - v;
    if (lane == 0) row_ptr[N] = E;
}

// ---- scan step 3: add block offsets, init cursors
__global__ __launch_bounds__(1024)
void scan3(int* __restrict__ row_ptr, int* __restrict__ cursor,
           const int* __restrict__ partials, int N)
{
    int i = blockIdx.x * 1024 + threadIdx.x;
    if (i >= N) return;
    int v = row_ptr[i] + partials[blockIdx.x];
    row_ptr[i] = v;
    cursor[i]  = v;
}

// ---- CSR build step 3: scatter src ids into per-dst slots
__global__ __launch_bounds__(256)
void csr_fill(const int* __restrict__ ei, int* __restrict__ cursor,
              int* __restrict__ csr_src, int E)
{
    int e = blockIdx.x * 256 + threadIdx.x;
    if (e >= E) return;
    int src = ei[e];
    int dst = ei[E + e];
    int pos = atomicAdd(&cursor[dst], 1);
    csr_src[pos] = src;
}

// ---- layer 1 + layer-2 projection, fused. One wave per node.
__global__ __launch_bounds__(256)
void sage1_fused(const int* __restrict__ row_ptr, const int* __restrict__ csr_src,
                 const __bf16* __restrict__ pq, const float* __restrict__ b1,
                 const float* __restrict__ W2l, const float* __restrict__ W2r,
                 float* __restrict__ r, float* __restrict__ s, int N)
{
    __shared__ float Wl[512], Wr[512];
    for (int i = threadIdx.x; i < 512; i += 256) {
        Wl[i] = W2l[i];
        Wr[i] = W2r[i];
    }
    __syncthreads();

    int wid  = threadIdx.x >> 6;
    int lane = threadIdx.x & 63;
    int n = blockIdx.x * 4 + wid;
    if (n >= N) return;
    int beg = row_ptr[n], end = row_ptr[n + 1];

    float ax = 0.f, ay = 0.f;
    for (int eb = beg; eb < end; eb += 64) {
        int cnt = min(64, end - eb);
        int id = (eb + lane < end) ? csr_src[eb + lane] : 0;
        for (int t = 0; t < cnt; ++t) {
            int src = __shfl(id, t);
            uint32_t w = *(const uint32_t*)(pq + (size_t)src * 256 + lane * 2);
            ax += bf16_lo(w);
            ay += bf16_hi(w);
        }
    }
    float inv = 1.0f / fmaxf((float)(end - beg), 1.0f);
    uint32_t qw = *(const uint32_t*)(pq + (size_t)n * 256 + 128 + lane * 2);
    float hx = fmaxf(ax * inv + b1[2 * lane]     + bf16_lo(qw), 0.f);
    float hy = fmaxf(ay * inv + b1[2 * lane + 1] + bf16_hi(qw), 0.f);

    float part[8];
    #pragma unroll
    for (int c = 0; c < 4; ++c) {
        part[c]     = hx * Wl[c * 128 + 2 * lane] + hy * Wl[c * 128 + 2 * lane + 1];
        part[4 + c] = hx * Wr[c * 128 + 2 * lane] + hy * Wr[c * 128 + 2 * lane + 1];
    }
    #pragma unroll
    for (int off = 32; off; off >>= 1)
        #pragma unroll
        for (int c = 0; c < 8; ++c)
            part[c] += __shfl_xor(part[c], off);
    if (lane == 0) {
        *(float4*)(r + (size_t)n * 4) = make_float4(part[0], part[1], part[2], part[3]);
        *(float4*)(s + (size_t)n * 4) = make_float4(part[4], part[5], part[6], part[7]);
    }
}

// ---- layer 2: out[n] = mean_{src} r[src] + b2 + s[n]
__global__ __launch_bounds__(256)
void sage2_gather(const int* __restrict__ row_ptr, const int* __restrict__ csr_src,
                  const float* __restrict__ r, const float* __restrict__ s,
                  const float* __restrict__ b2, float* __restrict__ out, int N)
{
    int t = blockIdx.x * 256 + threadIdx.x;
    if (t >= N * 4) return;
    int n = t >> 2, c = t & 3;
    int beg = row_ptr[n], end = row_ptr[n + 1];
    float acc = 0.f;
    for (int e = beg; e < end; ++e)
        acc += r[(size_t)csr_src[e] * 4 + c];
    out[t] = acc / fmaxf((float)(end - beg), 1.0f) + b2[c] + s[t];
}

extern "C" void kernel_launch(void* const* d_in, const int* in_sizes, int n_in,
                              void* d_out, int out_size, void* d_ws, size_t ws_size,
                              hipStream_t stream)
{
    const float* x   = (const float*)d_in[0];
    const int*   ei  = (const int*)d_in[1];
    const float* W1l = (const float*)d_in[2];
    const float* b1l = (const float*)d_in[3];
    const float* W1r = (const float*)d_in[4];
    const float* W2l = (const float*)d_in[5];
    const float* b2l = (const float*)d_in[6];
    const float* W2r = (const float*)d_in[7];
    float* out = (float*)d_out;

    const int N = in_sizes[0] / 768;   // 50000
    const int E = in_sizes[1] / 2;     // 800000
    const int NB = (N + 1023) / 1024;  // 49 scan blocks

    char* ws = (char*)d_ws;
    size_t off = 0;
    auto alloc = [&](size_t bytes) -> void* {
        void* pp = ws + off;
        off += (bytes + 255) & ~(size_t)255;
        return pp;
    };
    __bf16* pq      = (__bf16*)alloc((size_t)N * 256 * 2);
    float*  r       = (float*)alloc((size_t)N * 4 * 4);
    float*  s       = (float*)alloc((size_t)N * 4 * 4);
    __bf16* Wb      = (__bf16*)alloc((size_t)256 * 768 * 2);
    int*    deg     = (int*)alloc((size_t)N * 4);
    int*    row_ptr = (int*)alloc((size_t)(N + 1) * 4);
    int*    cursor  = (int*)alloc((size_t)N * 4);
    int*    csr_src = (int*)alloc((size_t)E * 4);
    int*    partials= (int*)alloc((size_t)64 * 4);

    // ---- fused layer-1 projection (bf16 MFMA): pq = x @ [W1l;W1r]^T
    convert_w<<<(256 * 768 + 255) / 256, 256, 0, stream>>>(W1l, W1r, Wb);
    dim3 gg(4, (N + 63) / 64);     // x = bn (fast) -> A-tile reuse in L2
    gemm_bf16<<<gg, 256, 0, stream>>>(x, Wb, pq, N);

    // ---- CSR build
    zero_deg<<<(N + 255) / 256, 256, 0, stream>>>(deg, N);
    csr_count<<<(E + 255) / 256, 256, 0, stream>>>(ei, deg, E);
    scan1<<<NB, 1024, 0, stream>>>(deg, row_ptr, partials, N);
    scan2<<<1, 64, 0, stream>>>(partials, NB, row_ptr, N, E);
    scan3<<<NB, 1024, 0, stream>>>(row_ptr, cursor, partials, N);
    csr_fill<<<(E + 255) / 256, 256, 0, stream>>>(ei, cursor, csr_src, E);

    // ---- layer 1 aggregate + epilogue + layer-2 projection (fused)
    sage1_fused<<<(N + 3) / 4, 256, 0, stream>>>(row_ptr, csr_src, pq, b1l,
                                                 W2l, W2r, r, s, N);

    // ---- layer 2 aggregate + epilogue
    sage2_gather<<<(N * 4 + 255) / 256, 256, 0, stream>>>(row_ptr, csr_src, r, s, b2l, out, N);
}

// Round 7
// 222.351 us; speedup vs baseline: 1.4794x; 1.2066x over previous
//
#include <hip/hip_runtime.h>

// ---------------------------------------------------------------------------
// TextGraphSAGE: 2-layer SAGEConv (mean aggr), N=50000, D=768, H=128, C=4,
// E=800000.
//  - project BEFORE aggregating (mean commutes with linear map)
//  - CSR gather instead of scatter atomics (r1: 102M float atomics = 77%)
//  - r5 lesson: LDS staging burst = MLP engine (direct-reg GEMM regressed)
//  - r6 lesson: BN<256 re-reads A (FETCH 2x); more blocks raise BW.
//  - r7: BN=256 single-pass (A read once) + 512-thread blocks (8 waves,
//    24 waves/CU); sage1 gather widened to 16B/lane, 4 edges in flight.
// ---------------------------------------------------------------------------

typedef __bf16 bf16x8 __attribute__((ext_vector_type(8)));
typedef float  f32x4  __attribute__((ext_vector_type(4)));

__device__ __forceinline__ float bf16_lo(uint32_t w) {
    union { uint32_t u; float f; } c; c.u = w << 16; return c.f;
}
__device__ __forceinline__ float bf16_hi(uint32_t w) {
    union { uint32_t u; float f; } c; c.u = w & 0xffff0000u; return c.f;
}

// ---- W pack: Wb[256][768] bf16 = concat(W1l, W1r) rows
__global__ __launch_bounds__(256)
void convert_w(const float* __restrict__ W1l, const float* __restrict__ W1r,
               __bf16* __restrict__ Wb)
{
    int i = blockIdx.x * 256 + threadIdx.x;
    if (i >= 256 * 768) return;
    int n = i / 768, k = i - n * 768;
    float v = (n < 128) ? W1l[n * 768 + k] : W1r[(n - 128) * 768 + k];
    Wb[i] = (__bf16)v;
}

// ---- fused layer-1 projection: pq[M][256](bf16) = x[M][768] @ Wb[256][768]^T
// 64x256 tile (full N in one pass -> A read once), 8 waves (2x4, 32x64 each),
// LDS staging + reg-prefetch pipeline. 46KB LDS -> 3 blocks/CU.
__global__ __launch_bounds__(512)
void gemm_bf16(const float* __restrict__ A, const __bf16* __restrict__ Bw,
               __bf16* __restrict__ Cb, int M)
{
    constexpr int LDK = 72;                  // +8 bf16 pad (144B row stride)
    __shared__ __bf16 As[64][LDK];           //  9.2 KB
    __shared__ __bf16 Bs[256][LDK];          // 36.9 KB
    const int bm   = blockIdx.x * 64;
    const int tid  = threadIdx.x;
    const int lane = tid & 63;
    const int wave = tid >> 6;               // 0..7
    const int wr = wave >> 2, wc = wave & 3; // wave tile: 32 rows x 64 cols
    const int l15 = lane & 15;
    const int lk  = lane >> 4;               // 0..3

    f32x4 acc[2][4] = {};
    float4 apref[2];
    bf16x8 bpref[4];

    const int arow = tid >> 3;               // 0..63
    const int akc  = (tid & 7) << 3;         // 0..56

    auto load_tile = [&](int k0) {
        if (bm + arow < M) {
            const float* src = A + (size_t)(bm + arow) * 768 + k0 + akc;
            apref[0] = *(const float4*)src;
            apref[1] = *(const float4*)(src + 4);
        } else {
            apref[0] = make_float4(0.f, 0.f, 0.f, 0.f);
            apref[1] = make_float4(0.f, 0.f, 0.f, 0.f);
        }
        #pragma unroll
        for (int it = 0; it < 4; ++it) {
            int v = it * 512 + tid;
            int row = v >> 3, kc = (v & 7) << 3;
            bpref[it] = *(const bf16x8*)(Bw + (size_t)row * 768 + k0 + kc);
        }
    };

    load_tile(0);
    for (int kt = 0; kt < 12; ++kt) {
        if (kt) __syncthreads();             // MFMA of kt-1 done with LDS
        {
            float4 f0 = apref[0], f1 = apref[1];
            bf16x8 b;
            b[0] = (__bf16)f0.x; b[1] = (__bf16)f0.y;
            b[2] = (__bf16)f0.z; b[3] = (__bf16)f0.w;
            b[4] = (__bf16)f1.x; b[5] = (__bf16)f1.y;
            b[6] = (__bf16)f1.z; b[7] = (__bf16)f1.w;
            *(bf16x8*)&As[arow][akc] = b;
        }
        #pragma unroll
        for (int it = 0; it < 4; ++it) {
            int v = it * 512 + tid;
            int row = v >> 3, kc = (v & 7) << 3;
            *(bf16x8*)&Bs[row][kc] = bpref[it];
        }
        __syncthreads();
        if (kt < 11) load_tile((kt + 1) * 64);   // in flight across MFMA

        #pragma unroll
        for (int ks = 0; ks < 2; ++ks) {
            int koff = ks * 32 + lk * 8;
            bf16x8 af[2], bfr[4];
            #pragma unroll
            for (int i = 0; i < 2; ++i)
                af[i] = *(const bf16x8*)&As[wr * 32 + i * 16 + l15][koff];
            #pragma unroll
            for (int j = 0; j < 4; ++j)
                bfr[j] = *(const bf16x8*)&Bs[wc * 64 + j * 16 + l15][koff];
            #pragma unroll
            for (int i = 0; i < 2; ++i)
                #pragma unroll
                for (int j = 0; j < 4; ++j)
                    acc[i][j] = __builtin_amdgcn_mfma_f32_16x16x32_bf16(
                        af[i], bfr[j], acc[i][j], 0, 0, 0);
        }
    }

    // C/D layout: col = lane&15, row = (lane>>4)*4 + reg  [m89-verified]
    #pragma unroll
    for (int i = 0; i < 2; ++i)
        #pragma unroll
        for (int j = 0; j < 4; ++j)
            #pragma unroll
            for (int v = 0; v < 4; ++v) {
                int row = bm + wr * 32 + i * 16 + lk * 4 + v;
                int col = wc * 64 + j * 16 + l15;
                if (row < M) Cb[(size_t)row * 256 + col] = (__bf16)acc[i][j][v];
            }
}

// ---- zero the degree array (hipMemsetAsync's blit kernel cost 87us)
__global__ __launch_bounds__(256)
void zero_deg(int* __restrict__ deg, int N)
{
    int i = blockIdx.x * 256 + threadIdx.x;
    if (i < N) deg[i] = 0;
}

// ---- CSR build step 1: degree histogram
__global__ __launch_bounds__(256)
void csr_count(const int* __restrict__ ei, int* __restrict__ deg, int E)
{
    int e = blockIdx.x * 256 + threadIdx.x;
    if (e >= E) return;
    atomicAdd(&deg[ei[E + e]], 1);
}

// ---- scan step 1: per-1024-block exclusive scan + block totals
__global__ __launch_bounds__(1024)
void scan1(const int* __restrict__ deg, int* __restrict__ row_ptr,
           int* __restrict__ partials, int N)
{
    __shared__ int buf[1024];
    int i = blockIdx.x * 1024 + threadIdx.x;
    int v = (i < N) ? deg[i] : 0;
    int val = v;
    buf[threadIdx.x] = val;
    __syncthreads();
    for (int off = 1; off < 1024; off <<= 1) {
        int t = (threadIdx.x >= (unsigned)off) ? buf[threadIdx.x - off] : 0;
        __syncthreads();
        val += t;
        buf[threadIdx.x] = val;
        __syncthreads();
    }
    if (i < N) row_ptr[i] = val - v;
    if (threadIdx.x == 1023) partials[blockIdx.x] = val;
}

// ---- scan step 2: exclusive scan of <=64 block totals (one wave)
__global__ __launch_bounds__(64)
void scan2(int* __restrict__ partials, int nb, int* __restrict__ row_ptr,
           int N, int E)
{
    int lane = threadIdx.x;
    int v = (lane < nb) ? partials[lane] : 0;
    int s = v;
    #pragma unroll
    for (int off = 1; off < 64; off <<= 1) {
        int t = __shfl_up(s, off);
        if (lane >= off) s += t;
    }
    if (lane < nb) partials[lane] = s - v;
    if (lane == 0) row_ptr[N] = E;
}

// ---- scan step 3: add block offsets, init cursors
__global__ __launch_bounds__(1024)
void scan3(int* __restrict__ row_ptr, int* __restrict__ cursor,
           const int* __restrict__ partials, int N)
{
    int i = blockIdx.x * 1024 + threadIdx.x;
    if (i >= N) return;
    int v = row_ptr[i] + partials[blockIdx.x];
    row_ptr[i] = v;
    cursor[i]  = v;
}

// ---- CSR build step 3: scatter src ids into per-dst slots
__global__ __launch_bounds__(256)
void csr_fill(const int* __restrict__ ei, int* __restrict__ cursor,
              int* __restrict__ csr_src, int E)
{
    int e = blockIdx.x * 256 + threadIdx.x;
    if (e >= E) return;
    int src = ei[e];
    int dst = ei[E + e];
    int pos = atomicAdd(&cursor[dst], 1);
    csr_src[pos] = src;
}

// ---- layer 1 + layer-2 projection, fused. One wave per node.
// 16 lanes per edge x 16B/lane -> 4 edges in flight per inner iteration.
// lane = g*16 + l: g = edge slot (0..3), l = feature block (8 feats).
__global__ __launch_bounds__(256)
void sage1_fused(const int* __restrict__ row_ptr, const int* __restrict__ csr_src,
                 const __bf16* __restrict__ pq, const float* __restrict__ b1,
                 const float* __restrict__ W2l, const float* __restrict__ W2r,
                 float* __restrict__ r, float* __restrict__ s, int N)
{
    __shared__ float Wl[512], Wr[512];
    for (int i = threadIdx.x; i < 512; i += 256) {
        Wl[i] = W2l[i];
        Wr[i] = W2r[i];
    }
    __syncthreads();

    int wid  = threadIdx.x >> 6;
    int lane = threadIdx.x & 63;
    int g = lane >> 4;          // edge slot 0..3
    int l = lane & 15;          // feature block 0..15 (8 feats each)
    int n = blockIdx.x * 4 + wid;
    if (n >= N) return;
    int beg = row_ptr[n], end = row_ptr[n + 1];

    float acc8[8] = {};
    for (int eb = beg; eb < end; eb += 64) {
        int cnt = min(64, end - eb);
        int id = (eb + lane < end) ? csr_src[eb + lane] : 0;
        for (int t = 0; t < cnt; t += 4) {
            int src = __shfl(id, t + g);
            if (t + g < cnt) {
                uint4 w = *(const uint4*)(pq + (size_t)src * 256 + l * 8);
                acc8[0] += bf16_lo(w.x); acc8[1] += bf16_hi(w.x);
                acc8[2] += bf16_lo(w.y); acc8[3] += bf16_hi(w.y);
                acc8[4] += bf16_lo(w.z); acc8[5] += bf16_hi(w.z);
                acc8[6] += bf16_lo(w.w); acc8[7] += bf16_hi(w.w);
            }
        }
    }
    // fold edge-slot partials: lanes with same l (g=0..3) hold same feat block
    #pragma unroll
    for (int c = 0; c < 8; ++c) {
        acc8[c] += __shfl_xor(acc8[c], 16);
        acc8[c] += __shfl_xor(acc8[c], 32);
    }

    float inv = 1.0f / fmaxf((float)(end - beg), 1.0f);
    uint4  qw  = *(const uint4*)(pq + (size_t)n * 256 + 128 + l * 8);
    float4 bv0 = *(const float4*)(b1 + l * 8);
    float4 bv1 = *(const float4*)(b1 + l * 8 + 4);
    float h[8];
    h[0] = fmaxf(acc8[0] * inv + bv0.x + bf16_lo(qw.x), 0.f);
    h[1] = fmaxf(acc8[1] * inv + bv0.y + bf16_hi(qw.x), 0.f);
    h[2] = fmaxf(acc8[2] * inv + bv0.z + bf16_lo(qw.y), 0.f);
    h[3] = fmaxf(acc8[3] * inv + bv0.w + bf16_hi(qw.y), 0.f);
    h[4] = fmaxf(acc8[4] * inv + bv1.x + bf16_lo(qw.z), 0.f);
    h[5] = fmaxf(acc8[5] * inv + bv1.y + bf16_hi(qw.z), 0.f);
    h[6] = fmaxf(acc8[6] * inv + bv1.z + bf16_lo(qw.w), 0.f);
    h[7] = fmaxf(acc8[7] * inv + bv1.w + bf16_hi(qw.w), 0.f);

    // proj2 inline: each lane dots its 8 feats; reduce across the 16 l-values
    float part[8];
    #pragma unroll
    for (int c = 0; c < 4; ++c) {
        float pl = 0.f, pr = 0.f;
        #pragma unroll
        for (int j = 0; j < 8; ++j) {
            pl = fmaf(h[j], Wl[c * 128 + l * 8 + j], pl);
            pr = fmaf(h[j], Wr[c * 128 + l * 8 + j], pr);
        }
        part[c] = pl; part[4 + c] = pr;
    }
    #pragma unroll
    for (int off = 8; off; off >>= 1)
        #pragma unroll
        for (int c = 0; c < 8; ++c)
            part[c] += __shfl_xor(part[c], off);
    if (lane == 0) {
        *(float4*)(r + (size_t)n * 4) = make_float4(part[0], part[1], part[2], part[3]);
        *(float4*)(s + (size_t)n * 4) = make_float4(part[4], part[5], part[6], part[7]);
    }
}

// ---- layer 2: out[n] = mean_{src} r[src] + b2 + s[n]
__global__ __launch_bounds__(256)
void sage2_gather(const int* __restrict__ row_ptr, const int* __restrict__ csr_src,
                  const float* __restrict__ r, const float* __restrict__ s,
                  const float* __restrict__ b2, float* __restrict__ out, int N)
{
    int t = blockIdx.x * 256 + threadIdx.x;
    if (t >= N * 4) return;
    int n = t >> 2, c = t & 3;
    int beg = row_ptr[n], end = row_ptr[n + 1];
    float acc = 0.f;
    for (int e = beg; e < end; ++e)
        acc += r[(size_t)csr_src[e] * 4 + c];
    out[t] = acc / fmaxf((float)(end - beg), 1.0f) + b2[c] + s[t];
}

extern "C" void kernel_launch(void* const* d_in, const int* in_sizes, int n_in,
                              void* d_out, int out_size, void* d_ws, size_t ws_size,
                              hipStream_t stream)
{
    const float* x   = (const float*)d_in[0];
    const int*   ei  = (const int*)d_in[1];
    const float* W1l = (const float*)d_in[2];
    const float* b1l = (const float*)d_in[3];
    const float* W1r = (const float*)d_in[4];
    const float* W2l = (const float*)d_in[5];
    const float* b2l = (const float*)d_in[6];
    const float* W2r = (const float*)d_in[7];
    float* out = (float*)d_out;

    const int N = in_sizes[0] / 768;   // 50000
    const int E = in_sizes[1] / 2;     // 800000
    const int NB = (N + 1023) / 1024;  // 49 scan blocks

    char* ws = (char*)d_ws;
    size_t off = 0;
    auto alloc = [&](size_t bytes) -> void* {
        void* pp = ws + off;
        off += (bytes + 255) & ~(size_t)255;
        return pp;
    };
    __bf16* pq      = (__bf16*)alloc((size_t)N * 256 * 2);
    float*  r       = (float*)alloc((size_t)N * 4 * 4);
    float*  s       = (float*)alloc((size_t)N * 4 * 4);
    __bf16* Wb      = (__bf16*)alloc((size_t)256 * 768 * 2);
    int*    deg     = (int*)alloc((size_t)N * 4);
    int*    row_ptr = (int*)alloc((size_t)(N + 1) * 4);
    int*    cursor  = (int*)alloc((size_t)N * 4);
    int*    csr_src = (int*)alloc((size_t)E * 4);
    int*    partials= (int*)alloc((size_t)64 * 4);

    // ---- fused layer-1 projection (bf16 MFMA): pq = x @ [W1l;W1r]^T
    convert_w<<<(256 * 768 + 255) / 256, 256, 0, stream>>>(W1l, W1r, Wb);
    gemm_bf16<<<(N + 63) / 64, 512, 0, stream>>>(x, Wb, pq, N);

    // ---- CSR build
    zero_deg<<<(N + 255) / 256, 256, 0, stream>>>(deg, N);
    csr_count<<<(E + 255) / 256, 256, 0, stream>>>(ei, deg, E);
    scan1<<<NB, 1024, 0, stream>>>(deg, row_ptr, partials, N);
    scan2<<<1, 64, 0, stream>>>(partials, NB, row_ptr, N, E);
    scan3<<<NB, 1024, 0, stream>>>(row_ptr, cursor, partials, N);
    csr_fill<<<(E + 255) / 256, 256, 0, stream>>>(ei, cursor, csr_src, E);

    // ---- layer 1 aggregate + epilogue + layer-2 projection (fused)
    sage1_fused<<<(N + 3) / 4, 256, 0, stream>>>(row_ptr, csr_src, pq, b1l,
                                                 W2l, W2r, r, s, N);

    // ---- layer 2 aggregate + epilogue
    sage2_gather<<<(N * 4 + 255) / 256, 256, 0, stream>>>(row_ptr, csr_src, r, s, b2l, out, N);
}

// Round 8
// 221.615 us; speedup vs baseline: 1.4844x; 1.0033x over previous
//
#include <hip/hip_runtime.h>

// ---------------------------------------------------------------------------
// TextGraphSAGE: 2-layer SAGEConv (mean aggr), N=50000, D=768, H=128, C=4,
// E=800000.
//  - project BEFORE aggregating (mean commutes with linear map)
//  - CSR gather instead of scatter atomics (r1: 102M float atomics = 77%)
//  - r5 lesson: LDS staging burst = MLP engine (keep A staged+prefetched)
//  - r6 lesson: BN=256 single pass so A (153.6MB) is read exactly once
//  - r7 profile: all our kernels < 85us (harness ws-poison fill now tops).
//    r8: B-tile LDS eliminated -- Wb repacked fragment-major so each lane
//    loads its MFMA B-fragment straight from L2 (384KB resident); LDS 9KB.
//    sage1: 8 edges in flight x 32B/lane (2x MLP of r7).
// ---------------------------------------------------------------------------

typedef __bf16 bf16x8 __attribute__((ext_vector_type(8)));
typedef float  f32x4  __attribute__((ext_vector_type(4)));

__device__ __forceinline__ float bf16_lo(uint32_t w) {
    union { uint32_t u; float f; } c; c.u = w << 16; return c.f;
}
__device__ __forceinline__ float bf16_hi(uint32_t w) {
    union { uint32_t u; float f; } c; c.u = w & 0xffff0000u; return c.f;
}

// ---- prep: pack W into fragment-major bf16 Bp[kg][col][8] (kg=k/8, 96x256x8)
//      element (col,k) -> Bp[(k>>3)*2048 + col*8 + (k&7)]; also zero deg.
__global__ __launch_bounds__(256)
void prep(const float* __restrict__ W1l, const float* __restrict__ W1r,
          __bf16* __restrict__ Bp, int* __restrict__ deg, int N)
{
    int i = blockIdx.x * 256 + threadIdx.x;
    if (i < N) deg[i] = 0;
    if (i < 256 * 768) {
        int col = i / 768, k = i - col * 768;
        float v = (col < 128) ? W1l[col * 768 + k] : W1r[(col - 128) * 768 + k];
        Bp[((k >> 3) << 11) + (col << 3) + (k & 7)] = (__bf16)v;
    }
}

// ---- fused layer-1 projection: pq[M][256](bf16) = x[M][768] @ W[256][768]^T
// 64x256 tile, 8 waves (2x4, 32x64 each). A: LDS-staged burst + 1-deep reg
// prefetch (r5 lesson). B: direct per-lane fragment loads from L2-resident
// packed Bp -- no LDS, no staging.
__global__ __launch_bounds__(512)
void gemm_bf16(const float* __restrict__ A, const __bf16* __restrict__ Bp,
               __bf16* __restrict__ Cb, int M)
{
    constexpr int LDK = 72;                  // +8 bf16 pad (144B row stride)
    __shared__ __bf16 As[64][LDK];           // 9.2 KB total LDS
    const int bm   = blockIdx.x * 64;
    const int tid  = threadIdx.x;
    const int lane = tid & 63;
    const int wave = tid >> 6;               // 0..7
    const int wr = wave >> 2, wc = wave & 3; // wave tile: 32 rows x 64 cols
    const int l15 = lane & 15;
    const int lk  = lane >> 4;               // 0..3

    f32x4 acc[2][4] = {};
    float4 apref[2];

    const int arow = tid >> 3;               // 0..63
    const int akc  = (tid & 7) << 3;         // 0..56
    // B fragment base: col = wc*64 + j*16 + l15, kg = kt*8 + ks*4 + lk
    const __bf16* bbase = Bp + ((size_t)(wc * 64 + l15) << 3) + ((size_t)lk << 11);

    auto load_A = [&](int k0) {
        if (bm + arow < M) {
            const float* src = A + (size_t)(bm + arow) * 768 + k0 + akc;
            apref[0] = *(const float4*)src;
            apref[1] = *(const float4*)(src + 4);
        } else {
            apref[0] = make_float4(0.f, 0.f, 0.f, 0.f);
            apref[1] = make_float4(0.f, 0.f, 0.f, 0.f);
        }
    };

    load_A(0);
    for (int kt = 0; kt < 12; ++kt) {
        if (kt) __syncthreads();             // MFMA of kt-1 done with LDS
        {
            float4 f0 = apref[0], f1 = apref[1];
            bf16x8 b;
            b[0] = (__bf16)f0.x; b[1] = (__bf16)f0.y;
            b[2] = (__bf16)f0.z; b[3] = (__bf16)f0.w;
            b[4] = (__bf16)f1.x; b[5] = (__bf16)f1.y;
            b[6] = (__bf16)f1.z; b[7] = (__bf16)f1.w;
            *(bf16x8*)&As[arow][akc] = b;
        }
        __syncthreads();
        if (kt < 11) load_A((kt + 1) * 64);  // A burst in flight across MFMA

        // B fragments for this K-tile: 8 x 16B direct loads (L2-resident)
        bf16x8 bcur[2][4];
        #pragma unroll
        for (int ks = 0; ks < 2; ++ks)
            #pragma unroll
            for (int j = 0; j < 4; ++j)
                bcur[ks][j] = *(const bf16x8*)(bbase +
                    (((size_t)(kt * 8 + ks * 4) << 11) + ((size_t)j << 7)));

        #pragma unroll
        for (int ks = 0; ks < 2; ++ks) {
            int koff = ks * 32 + lk * 8;
            bf16x8 af[2];
            #pragma unroll
            for (int i = 0; i < 2; ++i)
                af[i] = *(const bf16x8*)&As[wr * 32 + i * 16 + l15][koff];
            #pragma unroll
            for (int i = 0; i < 2; ++i)
                #pragma unroll
                for (int j = 0; j < 4; ++j)
                    acc[i][j] = __builtin_amdgcn_mfma_f32_16x16x32_bf16(
                        af[i], bcur[ks][j], acc[i][j], 0, 0, 0);
        }
    }

    // C/D layout: col = lane&15, row = (lane>>4)*4 + reg  [m89-verified]
    #pragma unroll
    for (int i = 0; i < 2; ++i)
        #pragma unroll
        for (int j = 0; j < 4; ++j)
            #pragma unroll
            for (int v = 0; v < 4; ++v) {
                int row = bm + wr * 32 + i * 16 + lk * 4 + v;
                int col = wc * 64 + j * 16 + l15;
                if (row < M) Cb[(size_t)row * 256 + col] = (__bf16)acc[i][j][v];
            }
}

// ---- CSR build step 1: degree histogram
__global__ __launch_bounds__(256)
void csr_count(const int* __restrict__ ei, int* __restrict__ deg, int E)
{
    int e = blockIdx.x * 256 + threadIdx.x;
    if (e >= E) return;
    atomicAdd(&deg[ei[E + e]], 1);
}

// ---- scan step 1: per-1024-block exclusive scan + block totals
__global__ __launch_bounds__(1024)
void scan1(const int* __restrict__ deg, int* __restrict__ row_ptr,
           int* __restrict__ partials, int N)
{
    __shared__ int buf[1024];
    int i = blockIdx.x * 1024 + threadIdx.x;
    int v = (i < N) ? deg[i] : 0;
    int val = v;
    buf[threadIdx.x] = val;
    __syncthreads();
    for (int off = 1; off < 1024; off <<= 1) {
        int t = (threadIdx.x >= (unsigned)off) ? buf[threadIdx.x - off] : 0;
        __syncthreads();
        val += t;
        buf[threadIdx.x] = val;
        __syncthreads();
    }
    if (i < N) row_ptr[i] = val - v;
    if (threadIdx.x == 1023) partials[blockIdx.x] = val;
}

// ---- scan step 2: exclusive scan of <=64 block totals (one wave)
__global__ __launch_bounds__(64)
void scan2(int* __restrict__ partials, int nb, int* __restrict__ row_ptr,
           int N, int E)
{
    int lane = threadIdx.x;
    int v = (lane < nb) ? partials[lane] : 0;
    int s = v;
    #pragma unroll
    for (int off = 1; off < 64; off <<= 1) {
        int t = __shfl_up(s, off);
        if (lane >= off) s += t;
    }
    if (lane < nb) partials[lane] = s - v;
    if (lane == 0) row_ptr[N] = E;
}

// ---- scan step 3: add block offsets, init cursors
__global__ __launch_bounds__(1024)
void scan3(int* __restrict__ row_ptr, int* __restrict__ cursor,
           const int* __restrict__ partials, int N)
{
    int i = blockIdx.x * 1024 + threadIdx.x;
    if (i >= N) return;
    int v = row_ptr[i] + partials[blockIdx.x];
    row_ptr[i] = v;
    cursor[i]  = v;
}

// ---- CSR build step 3: scatter src ids into per-dst slots
__global__ __launch_bounds__(256)
void csr_fill(const int* __restrict__ ei, int* __restrict__ cursor,
              int* __restrict__ csr_src, int E)
{
    int e = blockIdx.x * 256 + threadIdx.x;
    if (e >= E) return;
    int src = ei[e];
    int dst = ei[E + e];
    int pos = atomicAdd(&cursor[dst], 1);
    csr_src[pos] = src;
}

// ---- layer 1 + layer-2 projection, fused. One wave per node.
// 8 lanes per edge x 32B/lane (2 x uint4) -> 8 edges in flight / iteration.
// lane = g*8 + l: g = edge slot (0..7), l = feature block (2x8 feats).
__global__ __launch_bounds__(256)
void sage1_fused(const int* __restrict__ row_ptr, const int* __restrict__ csr_src,
                 const __bf16* __restrict__ pq, const float* __restrict__ b1,
                 const float* __restrict__ W2l, const float* __restrict__ W2r,
                 float* __restrict__ r, float* __restrict__ s, int N)
{
    __shared__ float Wl[512], Wr[512];
    for (int i = threadIdx.x; i < 512; i += 256) {
        Wl[i] = W2l[i];
        Wr[i] = W2r[i];
    }
    __syncthreads();

    int wid  = threadIdx.x >> 6;
    int lane = threadIdx.x & 63;
    int g = lane >> 3;          // edge slot 0..7
    int l = lane & 7;           // feature block 0..7
    int n = blockIdx.x * 4 + wid;
    if (n >= N) return;
    int beg = row_ptr[n], end = row_ptr[n + 1];

    float a0[8] = {}, a1[8] = {};   // feats l*8+j and 64+l*8+j
    for (int eb = beg; eb < end; eb += 64) {
        int cnt = min(64, end - eb);
        int id = (eb + lane < end) ? csr_src[eb + lane] : 0;
        for (int t = 0; t < cnt; t += 8) {
            int src = __shfl(id, t + g);
            if (t + g < cnt) {
                const __bf16* row = pq + (size_t)src * 256;
                uint4 w0 = *(const uint4*)(row + l * 8);
                uint4 w1 = *(const uint4*)(row + 64 + l * 8);
                a0[0] += bf16_lo(w0.x); a0[1] += bf16_hi(w0.x);
                a0[2] += bf16_lo(w0.y); a0[3] += bf16_hi(w0.y);
                a0[4] += bf16_lo(w0.z); a0[5] += bf16_hi(w0.z);
                a0[6] += bf16_lo(w0.w); a0[7] += bf16_hi(w0.w);
                a1[0] += bf16_lo(w1.x); a1[1] += bf16_hi(w1.x);
                a1[2] += bf16_lo(w1.y); a1[3] += bf16_hi(w1.y);
                a1[4] += bf16_lo(w1.z); a1[5] += bf16_hi(w1.z);
                a1[6] += bf16_lo(w1.w); a1[7] += bf16_hi(w1.w);
            }
        }
    }
    // fold edge-slot partials (g=0..7 share the same l)
    #pragma unroll
    for (int c = 0; c < 8; ++c) {
        a0[c] += __shfl_xor(a0[c], 8);  a1[c] += __shfl_xor(a1[c], 8);
        a0[c] += __shfl_xor(a0[c], 16); a1[c] += __shfl_xor(a1[c], 16);
        a0[c] += __shfl_xor(a0[c], 32); a1[c] += __shfl_xor(a1[c], 32);
    }

    float inv = 1.0f / fmaxf((float)(end - beg), 1.0f);
    const __bf16* qrow = pq + (size_t)n * 256 + 128;
    uint4  qw0 = *(const uint4*)(qrow + l * 8);
    uint4  qw1 = *(const uint4*)(qrow + 64 + l * 8);
    float4 bv00 = *(const float4*)(b1 + l * 8);
    float4 bv01 = *(const float4*)(b1 + l * 8 + 4);
    float4 bv10 = *(const float4*)(b1 + 64 + l * 8);
    float4 bv11 = *(const float4*)(b1 + 64 + l * 8 + 4);
    float h0[8], h1[8];
    h0[0] = fmaxf(a0[0] * inv + bv00.x + bf16_lo(qw0.x), 0.f);
    h0[1] = fmaxf(a0[1] * inv + bv00.y + bf16_hi(qw0.x), 0.f);
    h0[2] = fmaxf(a0[2] * inv + bv00.z + bf16_lo(qw0.y), 0.f);
    h0[3] = fmaxf(a0[3] * inv + bv00.w + bf16_hi(qw0.y), 0.f);
    h0[4] = fmaxf(a0[4] * inv + bv01.x + bf16_lo(qw0.z), 0.f);
    h0[5] = fmaxf(a0[5] * inv + bv01.y + bf16_hi(qw0.z), 0.f);
    h0[6] = fmaxf(a0[6] * inv + bv01.z + bf16_lo(qw0.w), 0.f);
    h0[7] = fmaxf(a0[7] * inv + bv01.w + bf16_hi(qw0.w), 0.f);
    h1[0] = fmaxf(a1[0] * inv + bv10.x + bf16_lo(qw1.x), 0.f);
    h1[1] = fmaxf(a1[1] * inv + bv10.y + bf16_hi(qw1.x), 0.f);
    h1[2] = fmaxf(a1[2] * inv + bv10.z + bf16_lo(qw1.y), 0.f);
    h1[3] = fmaxf(a1[3] * inv + bv10.w + bf16_hi(qw1.y), 0.f);
    h1[4] = fmaxf(a1[4] * inv + bv11.x + bf16_lo(qw1.z), 0.f);
    h1[5] = fmaxf(a1[5] * inv + bv11.y + bf16_hi(qw1.z), 0.f);
    h1[6] = fmaxf(a1[6] * inv + bv11.z + bf16_lo(qw1.w), 0.f);
    h1[7] = fmaxf(a1[7] * inv + bv11.w + bf16_hi(qw1.w), 0.f);

    // proj2 inline: lane dots its 16 feats; reduce across the 8 l-values
    float part[8];
    #pragma unroll
    for (int c = 0; c < 4; ++c) {
        float pl = 0.f, pr = 0.f;
        #pragma unroll
        for (int j = 0; j < 8; ++j) {
            pl = fmaf(h0[j], Wl[c * 128 + l * 8 + j], pl);
            pl = fmaf(h1[j], Wl[c * 128 + 64 + l * 8 + j], pl);
            pr = fmaf(h0[j], Wr[c * 128 + l * 8 + j], pr);
            pr = fmaf(h1[j], Wr[c * 128 + 64 + l * 8 + j], pr);
        }
        part[c] = pl; part[4 + c] = pr;
    }
    #pragma unroll
    for (int off = 4; off; off >>= 1)
        #pragma unroll
        for (int c = 0; c < 8; ++c)
            part[c] += __shfl_xor(part[c], off);
    if (lane == 0) {
        *(float4*)(r + (size_t)n * 4) = make_float4(part[0], part[1], part[2], part[3]);
        *(float4*)(s + (size_t)n * 4) = make_float4(part[4], part[5], part[6], part[7]);
    }
}

// ---- layer 2: out[n] = mean_{src} r[src] + b2 + s[n]
__global__ __launch_bounds__(256)
void sage2_gather(const int* __restrict__ row_ptr, const int* __restrict__ csr_src,
                  const float* __restrict__ r, const float* __restrict__ s,
                  const float* __restrict__ b2, float* __restrict__ out, int N)
{
    int t = blockIdx.x * 256 + threadIdx.x;
    if (t >= N * 4) return;
    int n = t >> 2, c = t & 3;
    int beg = row_ptr[n], end = row_ptr[n + 1];
    float acc = 0.f;
    for (int e = beg; e < end; ++e)
        acc += r[(size_t)csr_src[e] * 4 + c];
    out[t] = acc / fmaxf((float)(end - beg), 1.0f) + b2[c] + s[t];
}

extern "C" void kernel_launch(void* const* d_in, const int* in_sizes, int n_in,
                              void* d_out, int out_size, void* d_ws, size_t ws_size,
                              hipStream_t stream)
{
    const float* x   = (const float*)d_in[0];
    const int*   ei  = (const int*)d_in[1];
    const float* W1l = (const float*)d_in[2];
    const float* b1l = (const float*)d_in[3];
    const float* W1r = (const float*)d_in[4];
    const float* W2l = (const float*)d_in[5];
    const float* b2l = (const float*)d_in[6];
    const float* W2r = (const float*)d_in[7];
    float* out = (float*)d_out;

    const int N = in_sizes[0] / 768;   // 50000
    const int E = in_sizes[1] / 2;     // 800000
    const int NB = (N + 1023) / 1024;  // 49 scan blocks

    char* ws = (char*)d_ws;
    size_t off = 0;
    auto alloc = [&](size_t bytes) -> void* {
        void* pp = ws + off;
        off += (bytes + 255) & ~(size_t)255;
        return pp;
    };
    __bf16* pq      = (__bf16*)alloc((size_t)N * 256 * 2);
    float*  r       = (float*)alloc((size_t)N * 4 * 4);
    float*  s       = (float*)alloc((size_t)N * 4 * 4);
    __bf16* Bp      = (__bf16*)alloc((size_t)256 * 768 * 2);
    int*    deg     = (int*)alloc((size_t)N * 4);
    int*    row_ptr = (int*)alloc((size_t)(N + 1) * 4);
    int*    cursor  = (int*)alloc((size_t)N * 4);
    int*    csr_src = (int*)alloc((size_t)E * 4);
    int*    partials= (int*)alloc((size_t)64 * 4);

    // ---- pack W fragment-major + zero deg (one launch)
    prep<<<(256 * 768 + 255) / 256, 256, 0, stream>>>(W1l, W1r, Bp, deg, N);

    // ---- fused layer-1 projection (bf16 MFMA): pq = x @ [W1l;W1r]^T
    gemm_bf16<<<(N + 63) / 64, 512, 0, stream>>>(x, Bp, pq, N);

    // ---- CSR build
    csr_count<<<(E + 255) / 256, 256, 0, stream>>>(ei, deg, E);
    scan1<<<NB, 1024, 0, stream>>>(deg, row_ptr, partials, N);
    scan2<<<1, 64, 0, stream>>>(partials, NB, row_ptr, N, E);
    scan3<<<NB, 1024, 0, stream>>>(row_ptr, cursor, partials, N);
    csr_fill<<<(E + 255) / 256, 256, 0, stream>>>(ei, cursor, csr_src, E);

    // ---- layer 1 aggregate + epilogue + layer-2 projection (fused)
    sage1_fused<<<(N + 3) / 4, 256, 0, stream>>>(row_ptr, csr_src, pq, b1l,
                                                 W2l, W2r, r, s, N);

    // ---- layer 2 aggregate + epilogue
    sage2_gather<<<(N * 4 + 255) / 256, 256, 0, stream>>>(row_ptr, csr_src, r, s, b2l, out, N);
}

// Round 10
// 204.438 us; speedup vs baseline: 1.6091x; 1.0840x over previous
//
#include <hip/hip_runtime.h>

// ---------------------------------------------------------------------------
// TextGraphSAGE: 2-layer SAGEConv (mean aggr), N=50000, D=768, H=128, C=4,
// E=800000.
//  - project BEFORE aggregating (mean commutes with linear map)
//  - CSR gather instead of scatter atomics (r1: 102M float atomics = 77%)
//  - r5 lesson: LDS staging burst = MLP engine (keep A staged+prefetched)
//  - r6 lesson: BN=256 single pass so A (153.6MB) is read exactly once
//  - r8 lesson: per-kernel tweaks neutral; gap is serialization + the
//    vmcnt(0)-drain at every __syncthreads.
//  - r9: BK=128 (6 barrier periods); csr_fill fused INTO the gemm dispatch;
//    scan2 merged into scan3. FAILED: B-fragment kg offset double-counted
//    lk (bbase already holds lk<<11). r10 = r9 with that term removed.
// ---------------------------------------------------------------------------

typedef __bf16 bf16x8 __attribute__((ext_vector_type(8)));
typedef float  f32x4  __attribute__((ext_vector_type(4)));

__device__ __forceinline__ float bf16_lo(uint32_t w) {
    union { uint32_t u; float f; } c; c.u = w << 16; return c.f;
}
__device__ __forceinline__ float bf16_hi(uint32_t w) {
    union { uint32_t u; float f; } c; c.u = w & 0xffff0000u; return c.f;
}

// ---- prep: pack W into fragment-major bf16 Bp[kg][col][8] (kg=k/8, 96x256x8)
//      element (col,k) -> Bp[(k>>3)*2048 + col*8 + (k&7)]; also zero deg.
__global__ __launch_bounds__(256)
void prep(const float* __restrict__ W1l, const float* __restrict__ W1r,
          __bf16* __restrict__ Bp, int* __restrict__ deg, int N)
{
    int i = blockIdx.x * 256 + threadIdx.x;
    if (i < N) deg[i] = 0;
    if (i < 256 * 768) {
        int col = i / 768, k = i - col * 768;
        float v = (col < 128) ? W1l[col * 768 + k] : W1r[(col - 128) * 768 + k];
        Bp[((k >> 3) << 11) + (col << 3) + (k & 7)] = (__bf16)v;
    }
}

// ---- CSR build step 1: degree histogram
__global__ __launch_bounds__(256)
void csr_count(const int* __restrict__ ei, int* __restrict__ deg, int E)
{
    int e = blockIdx.x * 256 + threadIdx.x;
    if (e >= E) return;
    atomicAdd(&deg[ei[E + e]], 1);
}

// ---- scan step 1: per-1024-block exclusive scan + block totals
__global__ __launch_bounds__(1024)
void scan1(const int* __restrict__ deg, int* __restrict__ row_ptr,
           int* __restrict__ partials, int N)
{
    __shared__ int buf[1024];
    int i = blockIdx.x * 1024 + threadIdx.x;
    int v = (i < N) ? deg[i] : 0;
    int val = v;
    buf[threadIdx.x] = val;
    __syncthreads();
    for (int off = 1; off < 1024; off <<= 1) {
        int t = (threadIdx.x >= (unsigned)off) ? buf[threadIdx.x - off] : 0;
        __syncthreads();
        val += t;
        buf[threadIdx.x] = val;
        __syncthreads();
    }
    if (i < N) row_ptr[i] = val - v;
    if (threadIdx.x == 1023) partials[blockIdx.x] = val;
}

// ---- scan steps 2+3 merged: each block re-scans the <=64 partials with one
// wave (cheap), adds its offset, writes final row_ptr + cursor.
__global__ __launch_bounds__(1024)
void scan23(int* __restrict__ row_ptr, int* __restrict__ cursor,
            const int* __restrict__ partials, int N, int E, int nb)
{
    __shared__ int soff;
    int b = blockIdx.x;
    if (threadIdx.x < 64) {
        int lane = threadIdx.x;
        int v = (lane < nb) ? partials[lane] : 0;
        int s = v;
        #pragma unroll
        for (int off = 1; off < 64; off <<= 1) {
            int t = __shfl_up(s, off);
            if (lane >= off) s += t;
        }
        if (lane == b) soff = s - v;      // exclusive prefix for this block
    }
    __syncthreads();
    int off = soff;
    int i = b * 1024 + threadIdx.x;
    if (i < N) {
        int v = row_ptr[i] + off;
        row_ptr[i] = v;
        cursor[i]  = v;
    }
    if (b == 0 && threadIdx.x == 0) row_ptr[N] = E;
}

// ---- fused: gemm tiles (blocks < mtiles) + csr_fill (blocks >= mtiles).
// gemm: pq[M][256](bf16) = x[M][768] @ W[256][768]^T, 64x256 tile, 8 waves
// (2x4, 32x64 each), BK=128 (6 barrier periods), A LDS-staged + 1-deep reg
// prefetch, B direct per-lane fragment loads from L2-resident packed Bp.
__global__ __launch_bounds__(512)
void gemm_fill(const float* __restrict__ A, const __bf16* __restrict__ Bp,
               __bf16* __restrict__ Cb, int M, int mtiles,
               const int* __restrict__ ei, int* __restrict__ cursor,
               int* __restrict__ csr_src, int E)
{
    constexpr int LDK = 136;                 // 128 + 8 pad (272B row stride)
    __shared__ __bf16 As[64][LDK];           // 17.4 KB
    const int tid = threadIdx.x;

    if ((int)blockIdx.x >= mtiles) {
        // ---------------- csr_fill path (no LDS, no barriers) ----------------
        int stride = (gridDim.x - mtiles) * 512;
        for (int e = (blockIdx.x - mtiles) * 512 + tid; e < E; e += stride) {
            int src = ei[e];
            int dst = ei[E + e];
            int pos = atomicAdd(&cursor[dst], 1);
            csr_src[pos] = src;
        }
        return;
    }

    // ---------------- gemm path ----------------
    const int bm   = blockIdx.x * 64;
    const int lane = tid & 63;
    const int wave = tid >> 6;               // 0..7
    const int wr = wave >> 2, wc = wave & 3; // wave tile: 32 rows x 64 cols
    const int l15 = lane & 15;
    const int lk  = lane >> 4;               // 0..3

    f32x4 acc[2][4] = {};
    float4 apref[4];

    const int arow = tid >> 3;               // 0..63
    const int akc  = (tid & 7) << 4;         // 0..112 (16 floats/thread)
    const __bf16* bbase = Bp + ((size_t)(wc * 64 + l15) << 3) + ((size_t)lk << 11);

    auto load_A = [&](int k0) {
        if (bm + arow < M) {
            const float* src = A + (size_t)(bm + arow) * 768 + k0 + akc;
            apref[0] = *(const float4*)src;
            apref[1] = *(const float4*)(src + 4);
            apref[2] = *(const float4*)(src + 8);
            apref[3] = *(const float4*)(src + 12);
        } else {
            apref[0] = apref[1] = apref[2] = apref[3] = make_float4(0.f, 0.f, 0.f, 0.f);
        }
    };

    load_A(0);
    for (int kt = 0; kt < 6; ++kt) {
        if (kt) __syncthreads();             // MFMA of kt-1 done with LDS
        {
            bf16x8 b0, b1;
            b0[0] = (__bf16)apref[0].x; b0[1] = (__bf16)apref[0].y;
            b0[2] = (__bf16)apref[0].z; b0[3] = (__bf16)apref[0].w;
            b0[4] = (__bf16)apref[1].x; b0[5] = (__bf16)apref[1].y;
            b0[6] = (__bf16)apref[1].z; b0[7] = (__bf16)apref[1].w;
            b1[0] = (__bf16)apref[2].x; b1[1] = (__bf16)apref[2].y;
            b1[2] = (__bf16)apref[2].z; b1[3] = (__bf16)apref[2].w;
            b1[4] = (__bf16)apref[3].x; b1[5] = (__bf16)apref[3].y;
            b1[6] = (__bf16)apref[3].z; b1[7] = (__bf16)apref[3].w;
            *(bf16x8*)&As[arow][akc]     = b0;
            *(bf16x8*)&As[arow][akc + 8] = b1;
        }
        __syncthreads();
        if (kt < 5) load_A((kt + 1) * 128);  // burst in flight across MFMAs

        #pragma unroll
        for (int ksp = 0; ksp < 2; ++ksp) {  // two ks-pairs: caps B VGPRs
            bf16x8 bcur[2][4];
            #pragma unroll
            for (int k2 = 0; k2 < 2; ++k2)
                #pragma unroll
                for (int j = 0; j < 4; ++j)
                    bcur[k2][j] = *(const bf16x8*)(bbase +
                        (((size_t)(kt * 16 + (ksp * 2 + k2) * 4) << 11) +
                         ((size_t)j << 7)));          // kg: lk lives in bbase
            #pragma unroll
            for (int k2 = 0; k2 < 2; ++k2) {
                int koff = (ksp * 2 + k2) * 32 + lk * 8;
                bf16x8 af[2];
                #pragma unroll
                for (int i = 0; i < 2; ++i)
                    af[i] = *(const bf16x8*)&As[wr * 32 + i * 16 + l15][koff];
                #pragma unroll
                for (int i = 0; i < 2; ++i)
                    #pragma unroll
                    for (int j = 0; j < 4; ++j)
                        acc[i][j] = __builtin_amdgcn_mfma_f32_16x16x32_bf16(
                            af[i], bcur[k2][j], acc[i][j], 0, 0, 0);
            }
        }
    }

    // C/D layout: col = lane&15, row = (lane>>4)*4 + reg  [m89-verified]
    #pragma unroll
    for (int i = 0; i < 2; ++i)
        #pragma unroll
        for (int j = 0; j < 4; ++j)
            #pragma unroll
            for (int v = 0; v < 4; ++v) {
                int row = bm + wr * 32 + i * 16 + lk * 4 + v;
                int col = wc * 64 + j * 16 + l15;
                if (row < M) Cb[(size_t)row * 256 + col] = (__bf16)acc[i][j][v];
            }
}

// ---- layer 1 + layer-2 projection, fused. One wave per node.
// 8 lanes per edge x 32B/lane (2 x uint4) -> 8 edges in flight / iteration.
__global__ __launch_bounds__(256)
void sage1_fused(const int* __restrict__ row_ptr, const int* __restrict__ csr_src,
                 const __bf16* __restrict__ pq, const float* __restrict__ b1,
                 const float* __restrict__ W2l, const float* __restrict__ W2r,
                 float* __restrict__ r, float* __restrict__ s, int N)
{
    __shared__ float Wl[512], Wr[512];
    for (int i = threadIdx.x; i < 512; i += 256) {
        Wl[i] = W2l[i];
        Wr[i] = W2r[i];
    }
    __syncthreads();

    int wid  = threadIdx.x >> 6;
    int lane = threadIdx.x & 63;
    int g = lane >> 3;          // edge slot 0..7
    int l = lane & 7;           // feature block 0..7
    int n = blockIdx.x * 4 + wid;
    if (n >= N) return;
    int beg = row_ptr[n], end = row_ptr[n + 1];

    float a0[8] = {}, a1[8] = {};   // feats l*8+j and 64+l*8+j
    for (int eb = beg; eb < end; eb += 64) {
        int cnt = min(64, end - eb);
        int id = (eb + lane < end) ? csr_src[eb + lane] : 0;
        for (int t = 0; t < cnt; t += 8) {
            int src = __shfl(id, t + g);
            if (t + g < cnt) {
                const __bf16* row = pq + (size_t)src * 256;
                uint4 w0 = *(const uint4*)(row + l * 8);
                uint4 w1 = *(const uint4*)(row + 64 + l * 8);
                a0[0] += bf16_lo(w0.x); a0[1] += bf16_hi(w0.x);
                a0[2] += bf16_lo(w0.y); a0[3] += bf16_hi(w0.y);
                a0[4] += bf16_lo(w0.z); a0[5] += bf16_hi(w0.z);
                a0[6] += bf16_lo(w0.w); a0[7] += bf16_hi(w0.w);
                a1[0] += bf16_lo(w1.x); a1[1] += bf16_hi(w1.x);
                a1[2] += bf16_lo(w1.y); a1[3] += bf16_hi(w1.y);
                a1[4] += bf16_lo(w1.z); a1[5] += bf16_hi(w1.z);
                a1[6] += bf16_lo(w1.w); a1[7] += bf16_hi(w1.w);
            }
        }
    }
    #pragma unroll
    for (int c = 0; c < 8; ++c) {
        a0[c] += __shfl_xor(a0[c], 8);  a1[c] += __shfl_xor(a1[c], 8);
        a0[c] += __shfl_xor(a0[c], 16); a1[c] += __shfl_xor(a1[c], 16);
        a0[c] += __shfl_xor(a0[c], 32); a1[c] += __shfl_xor(a1[c], 32);
    }

    float inv = 1.0f / fmaxf((float)(end - beg), 1.0f);
    const __bf16* qrow = pq + (size_t)n * 256 + 128;
    uint4  qw0 = *(const uint4*)(qrow + l * 8);
    uint4  qw1 = *(const uint4*)(qrow + 64 + l * 8);
    float4 bv00 = *(const float4*)(b1 + l * 8);
    float4 bv01 = *(const float4*)(b1 + l * 8 + 4);
    float4 bv10 = *(const float4*)(b1 + 64 + l * 8);
    float4 bv11 = *(const float4*)(b1 + 64 + l * 8 + 4);
    float h0[8], h1[8];
    h0[0] = fmaxf(a0[0] * inv + bv00.x + bf16_lo(qw0.x), 0.f);
    h0[1] = fmaxf(a0[1] * inv + bv00.y + bf16_hi(qw0.x), 0.f);
    h0[2] = fmaxf(a0[2] * inv + bv00.z + bf16_lo(qw0.y), 0.f);
    h0[3] = fmaxf(a0[3] * inv + bv00.w + bf16_hi(qw0.y), 0.f);
    h0[4] = fmaxf(a0[4] * inv + bv01.x + bf16_lo(qw0.z), 0.f);
    h0[5] = fmaxf(a0[5] * inv + bv01.y + bf16_hi(qw0.z), 0.f);
    h0[6] = fmaxf(a0[6] * inv + bv01.z + bf16_lo(qw0.w), 0.f);
    h0[7] = fmaxf(a0[7] * inv + bv01.w + bf16_hi(qw0.w), 0.f);
    h1[0] = fmaxf(a1[0] * inv + bv10.x + bf16_lo(qw1.x), 0.f);
    h1[1] = fmaxf(a1[1] * inv + bv10.y + bf16_hi(qw1.x), 0.f);
    h1[2] = fmaxf(a1[2] * inv + bv10.z + bf16_lo(qw1.y), 0.f);
    h1[3] = fmaxf(a1[3] * inv + bv10.w + bf16_hi(qw1.y), 0.f);
    h1[4] = fmaxf(a1[4] * inv + bv11.x + bf16_lo(qw1.z), 0.f);
    h1[5] = fmaxf(a1[5] * inv + bv11.y + bf16_hi(qw1.z), 0.f);
    h1[6] = fmaxf(a1[6] * inv + bv11.z + bf16_lo(qw1.w), 0.f);
    h1[7] = fmaxf(a1[7] * inv + bv11.w + bf16_hi(qw1.w), 0.f);

    float part[8];
    #pragma unroll
    for (int c = 0; c < 4; ++c) {
        float pl = 0.f, pr = 0.f;
        #pragma unroll
        for (int j = 0; j < 8; ++j) {
            pl = fmaf(h0[j], Wl[c * 128 + l * 8 + j], pl);
            pl = fmaf(h1[j], Wl[c * 128 + 64 + l * 8 + j], pl);
            pr = fmaf(h0[j], Wr[c * 128 + l * 8 + j], pr);
            pr = fmaf(h1[j], Wr[c * 128 + 64 + l * 8 + j], pr);
        }
        part[c] = pl; part[4 + c] = pr;
    }
    #pragma unroll
    for (int off = 4; off; off >>= 1)
        #pragma unroll
        for (int c = 0; c < 8; ++c)
            part[c] += __shfl_xor(part[c], off);
    if (lane == 0) {
        *(float4*)(r + (size_t)n * 4) = make_float4(part[0], part[1], part[2], part[3]);
        *(float4*)(s + (size_t)n * 4) = make_float4(part[4], part[5], part[6], part[7]);
    }
}

// ---- layer 2: out[n] = mean_{src} r[src] + b2 + s[n]
__global__ __launch_bounds__(256)
void sage2_gather(const int* __restrict__ row_ptr, const int* __restrict__ csr_src,
                  const float* __restrict__ r, const float* __restrict__ s,
                  const float* __restrict__ b2, float* __restrict__ out, int N)
{
    int t = blockIdx.x * 256 + threadIdx.x;
    if (t >= N * 4) return;
    int n = t >> 2, c = t & 3;
    int beg = row_ptr[n], end = row_ptr[n + 1];
    float acc = 0.f;
    for (int e = beg; e < end; ++e)
        acc += r[(size_t)csr_src[e] * 4 + c];
    out[t] = acc / fmaxf((float)(end - beg), 1.0f) + b2[c] + s[t];
}

extern "C" void kernel_launch(void* const* d_in, const int* in_sizes, int n_in,
                              void* d_out, int out_size, void* d_ws, size_t ws_size,
                              hipStream_t stream)
{
    const float* x   = (const float*)d_in[0];
    const int*   ei  = (const int*)d_in[1];
    const float* W1l = (const float*)d_in[2];
    const float* b1l = (const float*)d_in[3];
    const float* W1r = (const float*)d_in[4];
    const float* W2l = (const float*)d_in[5];
    const float* b2l = (const float*)d_in[6];
    const float* W2r = (const float*)d_in[7];
    float* out = (float*)d_out;

    const int N = in_sizes[0] / 768;   // 50000
    const int E = in_sizes[1] / 2;     // 800000
    const int NB = (N + 1023) / 1024;  // 49 scan blocks

    char* ws = (char*)d_ws;
    size_t off = 0;
    auto alloc = [&](size_t bytes) -> void* {
        void* pp = ws + off;
        off += (bytes + 255) & ~(size_t)255;
        return pp;
    };
    __bf16* pq      = (__bf16*)alloc((size_t)N * 256 * 2);
    float*  r       = (float*)alloc((size_t)N * 4 * 4);
    float*  s       = (float*)alloc((size_t)N * 4 * 4);
    __bf16* Bp      = (__bf16*)alloc((size_t)256 * 768 * 2);
    int*    deg     = (int*)alloc((size_t)N * 4);
    int*    row_ptr = (int*)alloc((size_t)(N + 1) * 4);
    int*    cursor  = (int*)alloc((size_t)N * 4);
    int*    csr_src = (int*)alloc((size_t)E * 4);
    int*    partials= (int*)alloc((size_t)64 * 4);

    // ---- pack W fragment-major + zero deg
    prep<<<(256 * 768 + 255) / 256, 256, 0, stream>>>(W1l, W1r, Bp, deg, N);

    // ---- CSR: count + scan (fill happens inside gemm_fill)
    csr_count<<<(E + 255) / 256, 256, 0, stream>>>(ei, deg, E);
    scan1<<<NB, 1024, 0, stream>>>(deg, row_ptr, partials, N);
    scan23<<<NB, 1024, 0, stream>>>(row_ptr, cursor, partials, N, E, NB);

    // ---- fused layer-1 projection (bf16 MFMA) + csr_fill (independent
    //      chains overlap in one dispatch)
    const int mtiles = (N + 63) / 64;
    gemm_fill<<<mtiles + 256, 512, 0, stream>>>(x, Bp, pq, N, mtiles,
                                                ei, cursor, csr_src, E);

    // ---- layer 1 aggregate + epilogue + layer-2 projection (fused)
    sage1_fused<<<(N + 3) / 4, 256, 0, stream>>>(row_ptr, csr_src, pq, b1l,
                                                 W2l, W2r, r, s, N);

    // ---- layer 2 aggregate + epilogue
    sage2_gather<<<(N * 4 + 255) / 256, 256, 0, stream>>>(row_ptr, csr_src, r, s, b2l, out, N);
}